// Round 3
// baseline (573.853 us; speedup 1.0000x reference)
//
#include <hip/hip_runtime.h>
#include <cstddef>

#define NB 4
#define NP 8192
#define NK 16
#define NC 128
#define HW_ 136   // center_k LDS stride (shorts)
#define GIW 136   // stab gather/H stride (shorts): rel f32 tail @ +128
#define AGW 136
#define FSW 136

using short8   = __attribute__((ext_vector_type(8))) short;
using ushort4v = __attribute__((ext_vector_type(4))) unsigned short;
using floatx4  = __attribute__((ext_vector_type(4))) float;

__device__ __forceinline__ unsigned short f2bf(float f) {
    union { float f; unsigned u; } v; v.f = f;
    unsigned r = v.u + 0x7FFFu + ((v.u >> 16) & 1u);   // RNE
    return (unsigned short)(r >> 16);
}
__device__ __forceinline__ float bf2f(unsigned short u) {
    union { unsigned u; float f; } v; v.u = ((unsigned)u) << 16;
    return v.f;
}

#define MFMA(a, b, c) __builtin_amdgcn_mfma_f32_16x16x32_bf16((a), (b), (c), 0, 0, 0)

// ---------------------------------------------------------------------------
// Weight packing (unchanged from round 2).
// ---------------------------------------------------------------------------
__global__ void pack_weights_k(const float* __restrict__ offW1,
                               const float* __restrict__ eW1,
                               const float* __restrict__ eW2,
                               const float* __restrict__ uW1,
                               const float* __restrict__ uW2,
                               unsigned short* __restrict__ offW1p,
                               unsigned short* __restrict__ eW1fp,
                               unsigned short* __restrict__ eW2p,
                               unsigned short* __restrict__ uW1p,
                               unsigned short* __restrict__ uW2p)
{
    int i = blockIdx.x * 256 + threadIdx.x;
    if (i < 16384) { offW1p[i] = f2bf(offW1[i]); return; }
    i -= 16384;
    if (i < 49152) {
        int tt = i / 16384, rem = i % 16384;
        int o = rem / 128, k = rem % 128;
        eW1fp[i] = f2bf(eW1[(tt * 128 + o) * 131 + 3 + k]);
        return;
    }
    i -= 49152;
    if (i < 49152) { eW2p[i] = f2bf(eW2[i]); return; }
    i -= 49152;
    if (i < 98304) { uW1p[i] = f2bf(uW1[i]); return; }
    i -= 98304;
    if (i < 49152) { uW2p[i] = f2bf(uW2[i]); }
}

// ---------------------------------------------------------------------------
// center_k: 32 points/block. Offset MLP -> ctr; hoisted edge-L1 projection
// G = F @ W1f^T. G now bounced through LDS and written COALESCED (short8) —
// was 16 scattered 2B stores/thread.
// ---------------------------------------------------------------------------
__global__ __launch_bounds__(256, 4)
void center_k(const float* __restrict__ Fin, const float* __restrict__ xyz,
              const unsigned short* __restrict__ offW1p,
              const float* __restrict__ offW2, const float* __restrict__ offb1,
              const float* __restrict__ offb2,
              const unsigned short* __restrict__ eW1fp,
              unsigned short* __restrict__ Gbf, float* __restrict__ ctr)
{
    __shared__ __align__(16) unsigned short sA[32 * HW_];
    __shared__ __align__(16) unsigned short sH[32 * HW_];
    const int t = threadIdx.x, wv = t >> 6, ln = t & 63, q = ln >> 4, r = ln & 15;
    const int cg0 = wv << 1;
    const int base = blockIdx.x * 32;

    {   // 32x128 fp32 -> bf16 -> sA
        int row = t >> 3, c16 = (t & 7) * 16;
        const float* src = Fin + (size_t)(base + row) * NC + c16;
        float4 f0 = *(const float4*)src;
        float4 f1 = *(const float4*)(src + 4);
        float4 f2 = *(const float4*)(src + 8);
        float4 f3 = *(const float4*)(src + 12);
        short8 u0, u1;
        u0[0]=f2bf(f0.x); u0[1]=f2bf(f0.y); u0[2]=f2bf(f0.z); u0[3]=f2bf(f0.w);
        u0[4]=f2bf(f1.x); u0[5]=f2bf(f1.y); u0[6]=f2bf(f1.z); u0[7]=f2bf(f1.w);
        u1[0]=f2bf(f2.x); u1[1]=f2bf(f2.y); u1[2]=f2bf(f2.z); u1[3]=f2bf(f2.w);
        u1[4]=f2bf(f3.x); u1[5]=f2bf(f3.y); u1[6]=f2bf(f3.z); u1[7]=f2bf(f3.w);
        *(short8*)&sA[row * HW_ + c16]     = u0;
        *(short8*)&sA[row * HW_ + c16 + 8] = u1;
    }
    __syncthreads();

    floatx4 agk[2][2];   // G accumulators held across the barrier
    {   // offset L1 + G-GEMM, 2 row-tiles x 2 col-tiles per wave
        short8 wo[2][4], wg[2][4];
#pragma unroll
        for (int c = 0; c < 2; ++c)
#pragma unroll
            for (int ks = 0; ks < 4; ++ks) {
                wo[c][ks] = *(const short8*)(offW1p + ((cg0 + c) * 16 + r) * NC + ks * 32 + q * 8);
                wg[c][ks] = *(const short8*)(eW1fp  + ((cg0 + c) * 16 + r) * NC + ks * 32 + q * 8);
            }
        float bo[2] = { offb1[cg0 * 16 + r], offb1[(cg0 + 1) * 16 + r] };
#pragma unroll
        for (int rt = 0; rt < 2; ++rt) {
            short8 af[4];
#pragma unroll
            for (int ks = 0; ks < 4; ++ks)
                af[ks] = *(const short8*)&sA[(rt * 16 + r) * HW_ + ks * 32 + q * 8];
            floatx4 ao[2] = { {0.f,0.f,0.f,0.f}, {0.f,0.f,0.f,0.f} };
            floatx4 ag[2] = { {0.f,0.f,0.f,0.f}, {0.f,0.f,0.f,0.f} };
#pragma unroll
            for (int c = 0; c < 2; ++c)
#pragma unroll
                for (int ks = 0; ks < 4; ++ks) {
                    ao[c] = MFMA(af[ks], wo[c][ks], ao[c]);
                    ag[c] = MFMA(af[ks], wg[c][ks], ag[c]);
                }
#pragma unroll
            for (int c = 0; c < 2; ++c) {
                int col = (cg0 + c) * 16 + r;
#pragma unroll
                for (int i = 0; i < 4; ++i)
                    sH[(rt * 16 + q * 4 + i) * HW_ + col] = f2bf(fmaxf(ao[c][i] + bo[c], 0.f));
                agk[rt][c] = ag[c];
            }
        }
    }
    __syncthreads();   // sA reads done -> reuse sA as G staging

    {   // stage G -> sA (scalar LDS, cheap); offL2 runs concurrently on wv<2
#pragma unroll
        for (int rt = 0; rt < 2; ++rt)
#pragma unroll
            for (int c = 0; c < 2; ++c) {
                int col = (cg0 + c) * 16 + r;
#pragma unroll
                for (int i = 0; i < 4; ++i)
                    sA[(rt * 16 + q * 4 + i) * HW_ + col] = f2bf(agk[rt][c][i]);
            }
    }
    if (wv < 2) {   // offset L2 (out=3, zero-padded cols), one row-tile per wave
        int rt = wv;
        short8 wf[4];
#pragma unroll
        for (int ks = 0; ks < 4; ++ks) {
            short8 u = {0,0,0,0,0,0,0,0};
            if (r < 3) {
                const float* w = offW2 + r * NC + ks * 32 + q * 8;
                float4 f0 = *(const float4*)w;
                float4 f1 = *(const float4*)(w + 4);
                u[0]=f2bf(f0.x); u[1]=f2bf(f0.y); u[2]=f2bf(f0.z); u[3]=f2bf(f0.w);
                u[4]=f2bf(f1.x); u[5]=f2bf(f1.y); u[6]=f2bf(f1.z); u[7]=f2bf(f1.w);
            }
            wf[ks] = u;
        }
        short8 af[4];
#pragma unroll
        for (int ks = 0; ks < 4; ++ks)
            af[ks] = *(const short8*)&sH[(rt * 16 + r) * HW_ + ks * 32 + q * 8];
        floatx4 acc = {0.f, 0.f, 0.f, 0.f};
#pragma unroll
        for (int ks = 0; ks < 4; ++ks)
            acc = MFMA(af[ks], wf[ks], acc);
        if (r < 3) {
#pragma unroll
            for (int i = 0; i < 4; ++i) {
                int p = rt * 16 + q * 4 + i;
                ctr[(size_t)(base + p) * 3 + r] =
                    xyz[(size_t)(base + p) * 3 + r] + acc[i] + offb2[r];
            }
        }
    }
    __syncthreads();

    {   // coalesced Gbf write: 32 rows x 128 shorts
        int row = t >> 3, c16 = (t & 7) * 16;
        *(short8*)(Gbf + (size_t)(base + row) * NC + c16)     = *(short8*)&sA[row * HW_ + c16];
        *(short8*)(Gbf + (size_t)(base + row) * NC + c16 + 8) = *(short8*)&sA[row * HW_ + c16 + 8];
    }
}

// ---------------------------------------------------------------------------
// Fused iteration, 4-barrier flat schedule.
// P0: ALL global loads in one burst (knn -> both gather halves, all weight
//     fragments, biases, rel, self-feat) -> stage -> A
// L1' in-place relu(G + rel*W1r + b) over all 128 rows            -> B
// edge-L2: 64 MFMA/wave + maxK -> s_AGG                           -> C
// upd-L1 -> H2 (aliases s_GI rows 0..15); residual loads hoisted  -> D
// upd-L2 + residual store.
// __launch_bounds__(256,3): ~168 VGPR cap so the fragment sets stay
// register-resident (ILP). (256,4)'s 128-cap made the compiler allocate 64
// and issue every phase's loads just-in-time -> latency-bound at 98 us.
// LDS 43456 B -> 3 blocks/CU = measured residency at (256,4), so no loss.
// ---------------------------------------------------------------------------
__global__ __launch_bounds__(256, 3)
void stab_iter_k(const float* __restrict__ Fin, float* __restrict__ Fout,
                 const unsigned short* __restrict__ Gbf,
                 const float* __restrict__ xyz, const int* __restrict__ knn,
                 const float* __restrict__ ctr,
                 const float* __restrict__ eW1r,   // raw edge_W1 + t*128*131
                 const float* __restrict__ eb1, const float* __restrict__ eb2,
                 const unsigned short* __restrict__ eW2p,
                 const unsigned short* __restrict__ uW1p,
                 const unsigned short* __restrict__ uW2p,
                 const float* __restrict__ ub1, const float* __restrict__ ub2)
{
    __shared__ __align__(16) unsigned short s_GI[128 * GIW];  // 34816 B; H2 aliases rows 0..15
    __shared__ __align__(16) unsigned short s_AGG[16 * AGW];  // 4352 B (rows 8..15 garbage -> masked)
    __shared__ __align__(16) unsigned short s_FSB[8 * FSW];   // 2176 B  self features bf16
    __shared__ __align__(16) float s_W1R[4 * 132];            // 2112 B  rows 0-2: W1rel; row 3: eb1

    unsigned short* H2 = s_GI;

    // XCD swizzle: batch b -> XCDs {2b, 2b+1} (L2 locality for G gathers)
    const int xcd  = blockIdx.x & 7;
    const int slot = blockIdx.x >> 3;
    const int b    = xcd >> 1;
    const int n0   = ((slot << 1) | (xcd & 1)) << 3;
    const int t = threadIdx.x, wv = t >> 6, ln = t & 63;
    const int q = ln >> 4, r = ln & 15, cg0 = wv << 1;
    const int base = b * NP + n0;
    const int rr = t >> 4, c8 = (t & 15) * 8;

    // ======== P0: one burst of independent global loads ========
    const int* kb = knn + (size_t)base * NK;
    int kn[8];
#pragma unroll
    for (int j = 0; j < 8; ++j) kn[j] = kb[j * 16 + rr];
    short8 g[8];                                 // both gather halves
#pragma unroll
    for (int p = 0; p < 8; ++p)
        g[p] = *(const short8*)(Gbf + (size_t)(b * NP + kn[p]) * NC + c8);

    short8 wf2[2][4], wfa[2][8], wfb[2][4];      // all weight fragments
#pragma unroll
    for (int c = 0; c < 2; ++c) {
#pragma unroll
        for (int ks = 0; ks < 4; ++ks)
            wf2[c][ks] = *(const short8*)(eW2p + ((cg0 + c) * 16 + r) * NC + ks * 32 + q * 8);
#pragma unroll
        for (int ks = 0; ks < 8; ++ks)
            wfa[c][ks] = *(const short8*)(uW1p + ((cg0 + c) * 16 + r) * 256 + ks * 32 + q * 8);
#pragma unroll
        for (int ks = 0; ks < 4; ++ks)
            wfb[c][ks] = *(const short8*)(uW2p + ((cg0 + c) * 16 + r) * NC + ks * 32 + q * 8);
    }
    float eb2v[2] = { eb2[cg0 * 16 + r], eb2[(cg0 + 1) * 16 + r] };
    float ub1v[2] = { ub1[cg0 * 16 + r], ub1[(cg0 + 1) * 16 + r] };
    float ub2v[2] = { ub2[cg0 * 16 + r], ub2[(cg0 + 1) * 16 + r] };

    float rel0[3] = {0.f,0.f,0.f}, rel1[3] = {0.f,0.f,0.f};
    if (t < 64) {
        int nb0 = kb[t], nb1 = kb[64 + t];
        const float* x0  = xyz + (size_t)(b * NP + nb0) * 3;
        const float* x1  = xyz + (size_t)(b * NP + nb1) * 3;
        const float* c0p = ctr + (size_t)(base + (t >> 4)) * 3;
        const float* c1p = ctr + (size_t)(base + 4 + (t >> 4)) * 3;
#pragma unroll
        for (int j = 0; j < 3; ++j) { rel0[j] = x0[j] - c0p[j]; rel1[j] = x1[j] - c1p[j]; }
    }

    // ======== stage LDS ========
    {
        int row = t >> 5, c4 = (t & 31) << 2;
        float4 f = *(const float4*)(Fin + (size_t)(base + row) * NC + c4);
        ushort4v u = { f2bf(f.x), f2bf(f.y), f2bf(f.z), f2bf(f.w) };
        *(ushort4v*)&s_FSB[row * FSW + c4] = u;
    }
    if (t < 128) {
        int j = t >> 5, c0 = (t & 31) << 2;
#pragma unroll
        for (int k = 0; k < 4; ++k)
            s_W1R[j * 132 + c0 + k] = (j < 3) ? eW1r[(c0 + k) * 131 + j] : eb1[c0 + k];
    }
#pragma unroll
    for (int p = 0; p < 8; ++p)
        *(short8*)&s_GI[(p * 16 + rr) * GIW + c8] = g[p];
    if (t < 64) {
        float* r0 = (float*)&s_GI[t * GIW + 128];
        r0[0] = rel0[0]; r0[1] = rel0[1]; r0[2] = rel0[2];
        float* r1 = (float*)&s_GI[(64 + t) * GIW + 128];
        r1[0] = rel1[0]; r1[1] = rel1[1]; r1[2] = rel1[2];
    }
    __syncthreads();   // ======== A ========

    // ======== L1': H = relu(G + W1r*rel + b1) over 128 rows, in place ======
    {
        const int row = t >> 1, cb = (t & 1) << 6;
        const float* relp = (const float*)&s_GI[row * GIW + 128];
        float rl0 = relp[0], rl1 = relp[1], rl2 = relp[2];
#pragma unroll
        for (int gg = 0; gg < 8; ++gg) {
            int c0 = cb + gg * 8;
            short8 gv = *(short8*)&s_GI[row * GIW + c0];
            floatx4 w0a = *(const floatx4*)&s_W1R[0 * 132 + c0];
            floatx4 w0b = *(const floatx4*)&s_W1R[0 * 132 + c0 + 4];
            floatx4 w1a = *(const floatx4*)&s_W1R[1 * 132 + c0];
            floatx4 w1b = *(const floatx4*)&s_W1R[1 * 132 + c0 + 4];
            floatx4 w2a = *(const floatx4*)&s_W1R[2 * 132 + c0];
            floatx4 w2b = *(const floatx4*)&s_W1R[2 * 132 + c0 + 4];
            floatx4 bba = *(const floatx4*)&s_W1R[3 * 132 + c0];
            floatx4 bbb = *(const floatx4*)&s_W1R[3 * 132 + c0 + 4];
            short8 hv;
#pragma unroll
            for (int e = 0; e < 4; ++e) {
                float ha = bf2f((unsigned short)gv[e]) + bba[e];
                ha = fmaf(w0a[e], rl0, ha);
                ha = fmaf(w1a[e], rl1, ha);
                ha = fmaf(w2a[e], rl2, ha);
                hv[e] = (short)f2bf(fmaxf(ha, 0.f));
                float hb = bf2f((unsigned short)gv[e + 4]) + bbb[e];
                hb = fmaf(w0b[e], rl0, hb);
                hb = fmaf(w1b[e], rl1, hb);
                hb = fmaf(w2b[e], rl2, hb);
                hv[e + 4] = (short)f2bf(fmaxf(hb, 0.f));
            }
            *(short8*)&s_GI[row * GIW + c0] = hv;
        }
    }
    __syncthreads();   // ======== B ========

    // ======== edge L2 + max over K: 8 row-tiles (= 8 points) ========
#pragma unroll
    for (int rt = 0; rt < 8; ++rt) {
        short8 af[4];
#pragma unroll
        for (int ks = 0; ks < 4; ++ks)
            af[ks] = *(const short8*)&s_GI[(rt * 16 + r) * GIW + ks * 32 + q * 8];
        floatx4 acc[2] = { {0.f,0.f,0.f,0.f}, {0.f,0.f,0.f,0.f} };
#pragma unroll
        for (int c = 0; c < 2; ++c)
#pragma unroll
            for (int ks = 0; ks < 4; ++ks)
                acc[c] = MFMA(af[ks], wf2[c][ks], acc[c]);
#pragma unroll
        for (int c = 0; c < 2; ++c) {
            float m = fmaxf(fmaxf(acc[c][0], acc[c][1]), fmaxf(acc[c][2], acc[c][3]));
            m = fmaxf(m, __shfl_xor(m, 16));
            m = fmaxf(m, __shfl_xor(m, 32));
            if (q == 0)
                s_AGG[rt * AGW + (cg0 + c) * 16 + r] = f2bf(m + eb2v[c]);
        }
    }
    __syncthreads();   // ======== C ========

    // ======== update L1: [agg | self] (K=256) -> H2 ========
    {
        short8 af[8];
#pragma unroll
        for (int ks = 0; ks < 4; ++ks)
            af[ks] = *(const short8*)&s_AGG[r * AGW + ks * 32 + q * 8];
#pragma unroll
        for (int ks = 0; ks < 4; ++ks)
            af[4 + ks] = *(const short8*)&s_FSB[(r & 7) * FSW + ks * 32 + q * 8];
        floatx4 acc3[2] = { {0.f,0.f,0.f,0.f}, {0.f,0.f,0.f,0.f} };
#pragma unroll
        for (int c = 0; c < 2; ++c)
#pragma unroll
            for (int ks = 0; ks < 8; ++ks)
                acc3[c] = MFMA(af[ks], wfa[c][ks], acc3[c]);
#pragma unroll
        for (int c = 0; c < 2; ++c) {
#pragma unroll
            for (int i = 0; i < 4; ++i)
                H2[(q * 4 + i) * GIW + (cg0 + c) * 16 + r] =
                    f2bf(fmaxf(acc3[c][i] + ub1v[c], 0.f));
        }
    }
    // hoist residual fp32 loads (L2-hot) under this phase
    float rsd[2][4];
    if (q < 2) {
#pragma unroll
        for (int c = 0; c < 2; ++c)
#pragma unroll
            for (int i = 0; i < 4; ++i)
                rsd[c][i] = Fin[(size_t)(base + q * 4 + i) * NC + (cg0 + c) * 16 + r];
    }
    __syncthreads();   // ======== D ========

    // ======== update L2 + residual -> Fout ========
    {
        short8 af[4];
#pragma unroll
        for (int ks = 0; ks < 4; ++ks)
            af[ks] = *(const short8*)&H2[r * GIW + ks * 32 + q * 8];
        floatx4 acc[2] = { {0.f,0.f,0.f,0.f}, {0.f,0.f,0.f,0.f} };
#pragma unroll
        for (int c = 0; c < 2; ++c)
#pragma unroll
            for (int ks = 0; ks < 4; ++ks)
                acc[c] = MFMA(af[ks], wfb[c][ks], acc[c]);
        if (q < 2) {
#pragma unroll
            for (int c = 0; c < 2; ++c) {
#pragma unroll
                for (int i = 0; i < 4; ++i) {
                    int p = q * 4 + i;   // 0..7
                    Fout[(size_t)(base + p) * NC + (cg0 + c) * 16 + r] =
                        rsd[c][i] + acc[c][i] + ub2v[c];
                }
            }
        }
    }
}

// ---------------------------------------------------------------------------
extern "C" void kernel_launch(void* const* d_in, const int* in_sizes, int n_in,
                              void* d_out, int out_size, void* d_ws, size_t ws_size,
                              hipStream_t stream)
{
    const float* xyz   = (const float*)d_in[0];
    const float* feat  = (const float*)d_in[1];
    const int*   knn   = (const int*)d_in[2];
    const float* offW1 = (const float*)d_in[3];
    const float* offb1 = (const float*)d_in[4];
    const float* offW2 = (const float*)d_in[5];
    const float* offb2 = (const float*)d_in[6];
    const float* eW1   = (const float*)d_in[7];
    const float* eb1   = (const float*)d_in[8];
    const float* eW2   = (const float*)d_in[9];
    const float* eb2   = (const float*)d_in[10];
    const float* uW1   = (const float*)d_in[11];
    const float* ub1   = (const float*)d_in[12];
    const float* uW2   = (const float*)d_in[13];
    const float* ub2   = (const float*)d_in[14];
    float* out = (float*)d_out;

    char* ws = (char*)d_ws;
    unsigned short* Gbf    = (unsigned short*)ws;                 // 8388608 B
    float*          ctrb   = (float*)(ws + 8388608);              // 393216 B
    unsigned short* offW1p = (unsigned short*)(ws + 8781824);     // 32768 B
    unsigned short* eW1fp  = (unsigned short*)(ws + 8814592);     // 98304 B
    unsigned short* eW2p   = (unsigned short*)(ws + 8912896);     // 98304 B
    unsigned short* uW1p   = (unsigned short*)(ws + 9011200);     // 196608 B
    unsigned short* uW2p   = (unsigned short*)(ws + 9207808);     // 98304 B

    pack_weights_k<<<1024, 256, 0, stream>>>(offW1, eW1, eW2, uW1, uW2,
                                             offW1p, eW1fp, eW2p, uW1p, uW2p);

    const float* fin[3] = { feat, out, out };
    for (int tt = 0; tt < 3; ++tt) {
        center_k<<<1024, 256, 0, stream>>>(fin[tt], xyz, offW1p, offW2,
                                           offb1, offb2, eW1fp + tt * 16384,
                                           Gbf, ctrb);
        stab_iter_k<<<4096, 256, 0, stream>>>(
            fin[tt], out, Gbf, xyz, knn, ctrb,
            eW1 + tt * 128 * 131, eb1 + tt * 128, eb2 + tt * 128,
            eW2p + tt * 16384, uW1p + tt * 32768, uW2p + tt * 16384,
            ub1 + tt * 128, ub2 + tt * 128);
    }
}

// Round 4
// 374.122 us; speedup vs baseline: 1.5339x; 1.5339x over previous
//
#include <hip/hip_runtime.h>
#include <cstddef>

#define NB 4
#define NP 8192
#define NK 16
#define NC 128
#define HW_ 136   // center_k LDS stride (shorts)
#define GIW 136   // edge_k gather/H stride (shorts): rel f32 tail @ +128
#define AGW 136
#define UINW 264  // upd_k [agg|self] stride (shorts): 132 dw % 32 = 4 -> 2-way (free)
#define HUW 136

using short8   = __attribute__((ext_vector_type(8))) short;
using ushort4v = __attribute__((ext_vector_type(4))) unsigned short;
using floatx4  = __attribute__((ext_vector_type(4))) float;

__device__ __forceinline__ unsigned short f2bf(float f) {
    union { float f; unsigned u; } v; v.f = f;
    unsigned r = v.u + 0x7FFFu + ((v.u >> 16) & 1u);   // RNE
    return (unsigned short)(r >> 16);
}
__device__ __forceinline__ float bf2f(unsigned short u) {
    union { unsigned u; float f; } v; v.u = ((unsigned)u) << 16;
    return v.f;
}

#define MFMA(a, b, c) __builtin_amdgcn_mfma_f32_16x16x32_bf16((a), (b), (c), 0, 0, 0)

// ---------------------------------------------------------------------------
// Weight packing (unchanged).
// ---------------------------------------------------------------------------
__global__ void pack_weights_k(const float* __restrict__ offW1,
                               const float* __restrict__ eW1,
                               const float* __restrict__ eW2,
                               const float* __restrict__ uW1,
                               const float* __restrict__ uW2,
                               unsigned short* __restrict__ offW1p,
                               unsigned short* __restrict__ eW1fp,
                               unsigned short* __restrict__ eW2p,
                               unsigned short* __restrict__ uW1p,
                               unsigned short* __restrict__ uW2p)
{
    int i = blockIdx.x * 256 + threadIdx.x;
    if (i < 16384) { offW1p[i] = f2bf(offW1[i]); return; }
    i -= 16384;
    if (i < 49152) {
        int tt = i / 16384, rem = i % 16384;
        int o = rem / 128, k = rem % 128;
        eW1fp[i] = f2bf(eW1[(tt * 128 + o) * 131 + 3 + k]);
        return;
    }
    i -= 49152;
    if (i < 49152) { eW2p[i] = f2bf(eW2[i]); return; }
    i -= 49152;
    if (i < 98304) { uW1p[i] = f2bf(uW1[i]); return; }
    i -= 98304;
    if (i < 49152) { uW2p[i] = f2bf(uW2[i]); }
}

// ---------------------------------------------------------------------------
// center_k: initial iteration only (t=0). Offset MLP -> ctr; G = F @ W1f^T,
// Gbf written coalesced via LDS bounce. (Round-3 version; verified.)
// ---------------------------------------------------------------------------
__global__ __launch_bounds__(256, 4)
void center_k(const float* __restrict__ Fin, const float* __restrict__ xyz,
              const unsigned short* __restrict__ offW1p,
              const float* __restrict__ offW2, const float* __restrict__ offb1,
              const float* __restrict__ offb2,
              const unsigned short* __restrict__ eW1fp,
              unsigned short* __restrict__ Gbf, float* __restrict__ ctr)
{
    __shared__ __align__(16) unsigned short sA[32 * HW_];
    __shared__ __align__(16) unsigned short sH[32 * HW_];
    const int t = threadIdx.x, wv = t >> 6, ln = t & 63, q = ln >> 4, r = ln & 15;
    const int cg0 = wv << 1;
    const int base = blockIdx.x * 32;

    {   // 32x128 fp32 -> bf16 -> sA
        int row = t >> 3, c16 = (t & 7) * 16;
        const float* src = Fin + (size_t)(base + row) * NC + c16;
        float4 f0 = *(const float4*)src;
        float4 f1 = *(const float4*)(src + 4);
        float4 f2 = *(const float4*)(src + 8);
        float4 f3 = *(const float4*)(src + 12);
        short8 u0, u1;
        u0[0]=f2bf(f0.x); u0[1]=f2bf(f0.y); u0[2]=f2bf(f0.z); u0[3]=f2bf(f0.w);
        u0[4]=f2bf(f1.x); u0[5]=f2bf(f1.y); u0[6]=f2bf(f1.z); u0[7]=f2bf(f1.w);
        u1[0]=f2bf(f2.x); u1[1]=f2bf(f2.y); u1[2]=f2bf(f2.z); u1[3]=f2bf(f2.w);
        u1[4]=f2bf(f3.x); u1[5]=f2bf(f3.y); u1[6]=f2bf(f3.z); u1[7]=f2bf(f3.w);
        *(short8*)&sA[row * HW_ + c16]     = u0;
        *(short8*)&sA[row * HW_ + c16 + 8] = u1;
    }
    __syncthreads();

    floatx4 agk[2][2];
    {   // offset L1 + G-GEMM
        short8 wo[2][4], wg[2][4];
#pragma unroll
        for (int c = 0; c < 2; ++c)
#pragma unroll
            for (int ks = 0; ks < 4; ++ks) {
                wo[c][ks] = *(const short8*)(offW1p + ((cg0 + c) * 16 + r) * NC + ks * 32 + q * 8);
                wg[c][ks] = *(const short8*)(eW1fp  + ((cg0 + c) * 16 + r) * NC + ks * 32 + q * 8);
            }
        float bo[2] = { offb1[cg0 * 16 + r], offb1[(cg0 + 1) * 16 + r] };
#pragma unroll
        for (int rt = 0; rt < 2; ++rt) {
            short8 af[4];
#pragma unroll
            for (int ks = 0; ks < 4; ++ks)
                af[ks] = *(const short8*)&sA[(rt * 16 + r) * HW_ + ks * 32 + q * 8];
            floatx4 ao[2] = { {0.f,0.f,0.f,0.f}, {0.f,0.f,0.f,0.f} };
            floatx4 ag[2] = { {0.f,0.f,0.f,0.f}, {0.f,0.f,0.f,0.f} };
#pragma unroll
            for (int c = 0; c < 2; ++c)
#pragma unroll
                for (int ks = 0; ks < 4; ++ks) {
                    ao[c] = MFMA(af[ks], wo[c][ks], ao[c]);
                    ag[c] = MFMA(af[ks], wg[c][ks], ag[c]);
                }
#pragma unroll
            for (int c = 0; c < 2; ++c) {
                int col = (cg0 + c) * 16 + r;
#pragma unroll
                for (int i = 0; i < 4; ++i)
                    sH[(rt * 16 + q * 4 + i) * HW_ + col] = f2bf(fmaxf(ao[c][i] + bo[c], 0.f));
                agk[rt][c] = ag[c];
            }
        }
    }
    __syncthreads();

    {   // stage G -> sA
#pragma unroll
        for (int rt = 0; rt < 2; ++rt)
#pragma unroll
            for (int c = 0; c < 2; ++c) {
                int col = (cg0 + c) * 16 + r;
#pragma unroll
                for (int i = 0; i < 4; ++i)
                    sA[(rt * 16 + q * 4 + i) * HW_ + col] = f2bf(agk[rt][c][i]);
            }
    }
    if (wv < 2) {   // offset L2 (out=3)
        int rt = wv;
        short8 wf[4];
#pragma unroll
        for (int ks = 0; ks < 4; ++ks) {
            short8 u = {0,0,0,0,0,0,0,0};
            if (r < 3) {
                const float* w = offW2 + r * NC + ks * 32 + q * 8;
                float4 f0 = *(const float4*)w;
                float4 f1 = *(const float4*)(w + 4);
                u[0]=f2bf(f0.x); u[1]=f2bf(f0.y); u[2]=f2bf(f0.z); u[3]=f2bf(f0.w);
                u[4]=f2bf(f1.x); u[5]=f2bf(f1.y); u[6]=f2bf(f1.z); u[7]=f2bf(f1.w);
            }
            wf[ks] = u;
        }
        short8 af[4];
#pragma unroll
        for (int ks = 0; ks < 4; ++ks)
            af[ks] = *(const short8*)&sH[(rt * 16 + r) * HW_ + ks * 32 + q * 8];
        floatx4 acc = {0.f, 0.f, 0.f, 0.f};
#pragma unroll
        for (int ks = 0; ks < 4; ++ks)
            acc = MFMA(af[ks], wf[ks], acc);
        if (r < 3) {
#pragma unroll
            for (int i = 0; i < 4; ++i) {
                int p = rt * 16 + q * 4 + i;
                ctr[(size_t)(base + p) * 3 + r] =
                    xyz[(size_t)(base + p) * 3 + r] + acc[i] + offb2[r];
            }
        }
    }
    __syncthreads();

    {   // coalesced Gbf write
        int row = t >> 3, c16 = (t & 7) * 16;
        *(short8*)(Gbf + (size_t)(base + row) * NC + c16)     = *(short8*)&sA[row * HW_ + c16];
        *(short8*)(Gbf + (size_t)(base + row) * NC + c16 + 8) = *(short8*)&sA[row * HW_ + c16 + 8];
    }
}

// ---------------------------------------------------------------------------
// edge_k: round-2 proven edge pipeline, upd phases removed.
// gather G -> in-place L1' (G + W1r*rel + b, relu) -> edge L2 + maxK ->
// coalesced bf16 AGG dump. 8 points/block, grid 4096.
// LDS 21.7 KB; VGPR budget identical to round-2 (64 arch, no spill).
// ---------------------------------------------------------------------------
__global__ __launch_bounds__(256, 4)
void edge_k(const unsigned short* __restrict__ Gbf,
            const float* __restrict__ xyz, const int* __restrict__ knn,
            const float* __restrict__ ctr,
            const float* __restrict__ eW1r,   // raw edge_W1 + t*128*131
            const float* __restrict__ eb1, const float* __restrict__ eb2,
            const unsigned short* __restrict__ eW2p,
            unsigned short* __restrict__ aggG)
{
    __shared__ __align__(16) unsigned short s_GI[64 * GIW];   // 17408 B
    __shared__ __align__(16) unsigned short s_AGB[8 * AGW];   // 2176 B (bf16)
    __shared__ __align__(16) float s_W1R[4 * 132];            // 2112 B

    // XCD swizzle: batch b -> XCDs {2b, 2b+1}
    const int xcd  = blockIdx.x & 7;
    const int slot = blockIdx.x >> 3;
    const int b    = xcd >> 1;
    const int n0   = ((slot << 1) | (xcd & 1)) << 3;
    const int t = threadIdx.x, wv = t >> 6, ln = t & 63;
    const int q = ln >> 4, r = ln & 15, cg0 = wv << 1;
    const int base = b * NP + n0;
    const int rr = t >> 4, c8 = (t & 15) * 8;

    // ---- P0
    const int* kb = knn + (size_t)base * NK;
    int kn[8];
#pragma unroll
    for (int j = 0; j < 8; ++j) kn[j] = kb[j * 16 + rr];
    short8 g0[4];
#pragma unroll
    for (int p = 0; p < 4; ++p)
        g0[p] = *(const short8*)(Gbf + (size_t)(b * NP + kn[p]) * NC + c8);
    float rel0[3] = {0.f,0.f,0.f}, rel1[3] = {0.f,0.f,0.f};
    if (t < 64) {
        int nb0 = kb[t], nb1 = kb[64 + t];
        const float* x0  = xyz + (size_t)(b * NP + nb0) * 3;
        const float* x1  = xyz + (size_t)(b * NP + nb1) * 3;
        const float* c0p = ctr + (size_t)(base + (t >> 4)) * 3;
        const float* c1p = ctr + (size_t)(base + 4 + (t >> 4)) * 3;
#pragma unroll
        for (int j = 0; j < 3; ++j) { rel0[j] = x0[j] - c0p[j]; rel1[j] = x1[j] - c1p[j]; }
    }
    short8 wf2[2][4];
#pragma unroll
    for (int c = 0; c < 2; ++c)
#pragma unroll
        for (int ks = 0; ks < 4; ++ks)
            wf2[c][ks] = *(const short8*)(eW2p + ((cg0 + c) * 16 + r) * NC + ks * 32 + q * 8);
    float eb2v[2] = { eb2[cg0 * 16 + r], eb2[(cg0 + 1) * 16 + r] };

    // ---- stage LDS
    if (t < 128) {
        int j = t >> 5, c0 = (t & 31) << 2;
#pragma unroll
        for (int k = 0; k < 4; ++k)
            s_W1R[j * 132 + c0 + k] = (j < 3) ? eW1r[(c0 + k) * 131 + j] : eb1[c0 + k];
    }
#pragma unroll
    for (int p = 0; p < 4; ++p)
        *(short8*)&s_GI[(p * 16 + rr) * GIW + c8] = g0[p];
    if (t < 64) {
        float* relp = (float*)&s_GI[t * GIW + 128];
        relp[0] = rel0[0]; relp[1] = rel0[1]; relp[2] = rel0[2];
    }
    __syncthreads();

    // prefetch half-1 gather (flies under half-0 compute)
    short8 g1[4];
#pragma unroll
    for (int p = 0; p < 4; ++p)
        g1[p] = *(const short8*)(Gbf + (size_t)(b * NP + kn[4 + p]) * NC + c8);

#pragma unroll
    for (int h = 0; h < 2; ++h) {
        // ---- in-place L1': H = relu(G + W1r*rel + b1)
        {
            const int erow = t >> 2, ec0 = (t & 3) * 32;
            const float* relp = (const float*)&s_GI[erow * GIW + 128];
            float rl0 = relp[0], rl1 = relp[1], rl2 = relp[2];
#pragma unroll
            for (int g = 0; g < 4; ++g) {
                int c0 = ec0 + g * 8;
                short8 gv = *(short8*)&s_GI[erow * GIW + c0];
                floatx4 w0a = *(const floatx4*)&s_W1R[0 * 132 + c0];
                floatx4 w0b = *(const floatx4*)&s_W1R[0 * 132 + c0 + 4];
                floatx4 w1a = *(const floatx4*)&s_W1R[1 * 132 + c0];
                floatx4 w1b = *(const floatx4*)&s_W1R[1 * 132 + c0 + 4];
                floatx4 w2a = *(const floatx4*)&s_W1R[2 * 132 + c0];
                floatx4 w2b = *(const floatx4*)&s_W1R[2 * 132 + c0 + 4];
                floatx4 bba = *(const floatx4*)&s_W1R[3 * 132 + c0];
                floatx4 bbb = *(const floatx4*)&s_W1R[3 * 132 + c0 + 4];
                short8 hv;
#pragma unroll
                for (int e = 0; e < 4; ++e) {
                    float ha = bf2f((unsigned short)gv[e]) + bba[e];
                    ha = fmaf(w0a[e], rl0, ha);
                    ha = fmaf(w1a[e], rl1, ha);
                    ha = fmaf(w2a[e], rl2, ha);
                    hv[e] = (short)f2bf(fmaxf(ha, 0.f));
                    float hb = bf2f((unsigned short)gv[e + 4]) + bbb[e];
                    hb = fmaf(w0b[e], rl0, hb);
                    hb = fmaf(w1b[e], rl1, hb);
                    hb = fmaf(w2b[e], rl2, hb);
                    hv[e + 4] = (short)f2bf(fmaxf(hb, 0.f));
                }
                *(short8*)&s_GI[erow * GIW + c0] = hv;
            }
        }
        __syncthreads();

        // ---- edge L2 + max over K
#pragma unroll
        for (int rt = 0; rt < 4; ++rt) {
            short8 af[4];
#pragma unroll
            for (int ks = 0; ks < 4; ++ks)
                af[ks] = *(const short8*)&s_GI[(rt * 16 + r) * GIW + ks * 32 + q * 8];
            floatx4 acc[2] = { {0.f,0.f,0.f,0.f}, {0.f,0.f,0.f,0.f} };
#pragma unroll
            for (int c = 0; c < 2; ++c)
#pragma unroll
                for (int ks = 0; ks < 4; ++ks)
                    acc[c] = MFMA(af[ks], wf2[c][ks], acc[c]);
#pragma unroll
            for (int c = 0; c < 2; ++c) {
                float m = fmaxf(fmaxf(acc[c][0], acc[c][1]), fmaxf(acc[c][2], acc[c][3]));
                m = fmaxf(m, __shfl_xor(m, 16));
                m = fmaxf(m, __shfl_xor(m, 32));
                if (q == 0)
                    s_AGB[(h * 4 + rt) * AGW + (cg0 + c) * 16 + r] = f2bf(m + eb2v[c]);
            }
        }
        __syncthreads();

        if (h == 0) {
#pragma unroll
            for (int p = 0; p < 4; ++p)
                *(short8*)&s_GI[(p * 16 + rr) * GIW + c8] = g1[p];
            if (t < 64) {
                float* relp = (float*)&s_GI[t * GIW + 128];
                relp[0] = rel1[0]; relp[1] = rel1[1]; relp[2] = rel1[2];
            }
            __syncthreads();
        }
    }

    // ---- coalesced AGG dump (bf16)
    if (t < 128) {
        int row = t >> 4, cc = (t & 15) * 8;
        *(short8*)(aggG + (size_t)(base + row) * NC + cc) = *(short8*)&s_AGB[row * AGW + cc];
    }
}

// ---------------------------------------------------------------------------
// upd_k: 16 points/block, grid 2048, fully coalesced.
// P0 stage UIN=[agg|self] -> A -> upd-L1 -> H -> B -> upd-L2 + residual ->
// Fout + Fnew(LDS) -> C -> [G' = Fnew*W1f^T -> UIN; off-L1 -> H] -> D ->
// [coalesced Gbf dump; off-L2 (wave0) -> ctr'].  Phases C/D only if doNext.
// This replaces center_k for iterations 1,2 (fuses it with the update).
// ---------------------------------------------------------------------------
__global__ __launch_bounds__(256, 4)
void upd_k(const float* __restrict__ Fin, float* __restrict__ Fout,
           const unsigned short* __restrict__ aggG,
           const float* __restrict__ xyz,
           const unsigned short* __restrict__ uW1p,
           const unsigned short* __restrict__ uW2p,
           const float* __restrict__ ub1, const float* __restrict__ ub2,
           const unsigned short* __restrict__ eW1fpN,   // next iter G-proj
           const unsigned short* __restrict__ offW1p,
           const float* __restrict__ offW2, const float* __restrict__ offb1,
           const float* __restrict__ offb2,
           unsigned short* __restrict__ Gbf, float* __restrict__ ctrOut,
           int doNext)
{
    __shared__ __align__(16) unsigned short s_UIN[16 * UINW];  // 8448 B
    __shared__ __align__(16) unsigned short s_H[16 * HUW];     // 4352 B
    __shared__ __align__(16) unsigned short s_FN[16 * HUW];    // 4352 B

    const int t = threadIdx.x, wv = t >> 6, ln = t & 63;
    const int q = ln >> 4, r = ln & 15, cg0 = wv << 1;
    const int base = blockIdx.x * 16;          // global row over B*N
    const int row16 = t >> 4, c8 = (t & 15) * 8;

    // ---- P0: stage UIN = [agg(bf16) | self(f32->bf16)]
    {
        short8 av = *(const short8*)(aggG + (size_t)(base + row16) * NC + c8);
        *(short8*)&s_UIN[row16 * UINW + c8] = av;
        const float* src = Fin + (size_t)(base + row16) * NC + c8;
        float4 f0 = *(const float4*)src;
        float4 f1 = *(const float4*)(src + 4);
        short8 u;
        u[0]=f2bf(f0.x); u[1]=f2bf(f0.y); u[2]=f2bf(f0.z); u[3]=f2bf(f0.w);
        u[4]=f2bf(f1.x); u[5]=f2bf(f1.y); u[6]=f2bf(f1.z); u[7]=f2bf(f1.w);
        *(short8*)&s_UIN[row16 * UINW + 128 + c8] = u;
    }
    __syncthreads();   // ==== A ====

    // ---- upd-L1 (K=256) -> H
    {
        short8 wfa[2][8];
#pragma unroll
        for (int c = 0; c < 2; ++c)
#pragma unroll
            for (int ks = 0; ks < 8; ++ks)
                wfa[c][ks] = *(const short8*)(uW1p + ((cg0 + c) * 16 + r) * 256 + ks * 32 + q * 8);
        float ub1v[2] = { ub1[cg0 * 16 + r], ub1[(cg0 + 1) * 16 + r] };
        short8 af[8];
#pragma unroll
        for (int ks = 0; ks < 8; ++ks)
            af[ks] = *(const short8*)&s_UIN[r * UINW + ks * 32 + q * 8];
        floatx4 acc3[2] = { {0.f,0.f,0.f,0.f}, {0.f,0.f,0.f,0.f} };
#pragma unroll
        for (int c = 0; c < 2; ++c)
#pragma unroll
            for (int ks = 0; ks < 8; ++ks)
                acc3[c] = MFMA(af[ks], wfa[c][ks], acc3[c]);
#pragma unroll
        for (int c = 0; c < 2; ++c)
#pragma unroll
            for (int i = 0; i < 4; ++i)
                s_H[(q * 4 + i) * HUW + (cg0 + c) * 16 + r] =
                    f2bf(fmaxf(acc3[c][i] + ub1v[c], 0.f));
    }
    __syncthreads();   // ==== B ====

    // ---- upd-L2 + residual -> Fout; Fnew bf16 -> s_FN
    {
        short8 wfb[2][4];
#pragma unroll
        for (int c = 0; c < 2; ++c)
#pragma unroll
            for (int ks = 0; ks < 4; ++ks)
                wfb[c][ks] = *(const short8*)(uW2p + ((cg0 + c) * 16 + r) * NC + ks * 32 + q * 8);
        float ub2v[2] = { ub2[cg0 * 16 + r], ub2[(cg0 + 1) * 16 + r] };
        short8 af[4];
#pragma unroll
        for (int ks = 0; ks < 4; ++ks)
            af[ks] = *(const short8*)&s_H[r * HUW + ks * 32 + q * 8];
        floatx4 acc[2] = { {0.f,0.f,0.f,0.f}, {0.f,0.f,0.f,0.f} };
#pragma unroll
        for (int c = 0; c < 2; ++c)
#pragma unroll
            for (int ks = 0; ks < 4; ++ks)
                acc[c] = MFMA(af[ks], wfb[c][ks], acc[c]);
#pragma unroll
        for (int c = 0; c < 2; ++c) {
            int col = (cg0 + c) * 16 + r;
#pragma unroll
            for (int i = 0; i < 4; ++i) {
                int p = q * 4 + i;   // 0..15
                float fnew = Fin[(size_t)(base + p) * NC + col] + acc[c][i] + ub2v[c];
                Fout[(size_t)(base + p) * NC + col] = fnew;
                s_FN[p * HUW + col] = f2bf(fnew);
            }
        }
    }

    if (doNext) {
        __syncthreads();   // ==== C ====
        // ---- G' = Fnew*W1f^T -> s_UIN (agg region, dead); off-L1 -> s_H
        {
            short8 wg[2][4], wo[2][4];
#pragma unroll
            for (int c = 0; c < 2; ++c)
#pragma unroll
                for (int ks = 0; ks < 4; ++ks) {
                    wg[c][ks] = *(const short8*)(eW1fpN + ((cg0 + c) * 16 + r) * NC + ks * 32 + q * 8);
                    wo[c][ks] = *(const short8*)(offW1p + ((cg0 + c) * 16 + r) * NC + ks * 32 + q * 8);
                }
            float bo[2] = { offb1[cg0 * 16 + r], offb1[(cg0 + 1) * 16 + r] };
            short8 af[4];
#pragma unroll
            for (int ks = 0; ks < 4; ++ks)
                af[ks] = *(const short8*)&s_FN[r * HUW + ks * 32 + q * 8];
            floatx4 ag[2] = { {0.f,0.f,0.f,0.f}, {0.f,0.f,0.f,0.f} };
            floatx4 ao[2] = { {0.f,0.f,0.f,0.f}, {0.f,0.f,0.f,0.f} };
#pragma unroll
            for (int c = 0; c < 2; ++c)
#pragma unroll
                for (int ks = 0; ks < 4; ++ks) {
                    ag[c] = MFMA(af[ks], wg[c][ks], ag[c]);
                    ao[c] = MFMA(af[ks], wo[c][ks], ao[c]);
                }
#pragma unroll
            for (int c = 0; c < 2; ++c) {
                int col = (cg0 + c) * 16 + r;
#pragma unroll
                for (int i = 0; i < 4; ++i) {
                    int p = q * 4 + i;
                    s_UIN[p * UINW + col] = f2bf(ag[c][i]);
                    s_H[p * HUW + col]    = f2bf(fmaxf(ao[c][i] + bo[c], 0.f));
                }
            }
        }
        __syncthreads();   // ==== D ====

        // coalesced Gbf dump
        *(short8*)(Gbf + (size_t)(base + row16) * NC + c8) =
            *(short8*)&s_UIN[row16 * UINW + c8];

        if (wv == 0) {   // off-L2 (out=3) -> ctr'
            short8 wf[4];
#pragma unroll
            for (int ks = 0; ks < 4; ++ks) {
                short8 u = {0,0,0,0,0,0,0,0};
                if (r < 3) {
                    const float* w = offW2 + r * NC + ks * 32 + q * 8;
                    float4 f0 = *(const float4*)w;
                    float4 f1 = *(const float4*)(w + 4);
                    u[0]=f2bf(f0.x); u[1]=f2bf(f0.y); u[2]=f2bf(f0.z); u[3]=f2bf(f0.w);
                    u[4]=f2bf(f1.x); u[5]=f2bf(f1.y); u[6]=f2bf(f1.z); u[7]=f2bf(f1.w);
                }
                wf[ks] = u;
            }
            short8 af[4];
#pragma unroll
            for (int ks = 0; ks < 4; ++ks)
                af[ks] = *(const short8*)&s_H[r * HUW + ks * 32 + q * 8];
            floatx4 acc = {0.f, 0.f, 0.f, 0.f};
#pragma unroll
            for (int ks = 0; ks < 4; ++ks)
                acc = MFMA(af[ks], wf[ks], acc);
            if (r < 3) {
#pragma unroll
                for (int i = 0; i < 4; ++i) {
                    int p = q * 4 + i;   // 0..15
                    ctrOut[(size_t)(base + p) * 3 + r] =
                        xyz[(size_t)(base + p) * 3 + r] + acc[i] + offb2[r];
                }
            }
        }
    }
}

// ---------------------------------------------------------------------------
extern "C" void kernel_launch(void* const* d_in, const int* in_sizes, int n_in,
                              void* d_out, int out_size, void* d_ws, size_t ws_size,
                              hipStream_t stream)
{
    const float* xyz   = (const float*)d_in[0];
    const float* feat  = (const float*)d_in[1];
    const int*   knn   = (const int*)d_in[2];
    const float* offW1 = (const float*)d_in[3];
    const float* offb1 = (const float*)d_in[4];
    const float* offW2 = (const float*)d_in[5];
    const float* offb2 = (const float*)d_in[6];
    const float* eW1   = (const float*)d_in[7];
    const float* eb1   = (const float*)d_in[8];
    const float* eW2   = (const float*)d_in[9];
    const float* eb2   = (const float*)d_in[10];
    const float* uW1   = (const float*)d_in[11];
    const float* ub1   = (const float*)d_in[12];
    const float* uW2   = (const float*)d_in[13];
    const float* ub2   = (const float*)d_in[14];
    float* out = (float*)d_out;

    char* ws = (char*)d_ws;
    unsigned short* Gbf    = (unsigned short*)ws;                 // 8388608 B
    float*          ctrb   = (float*)(ws + 8388608);              // 393216 B
    unsigned short* offW1p = (unsigned short*)(ws + 8781824);     // 32768 B
    unsigned short* eW1fp  = (unsigned short*)(ws + 8814592);     // 98304 B
    unsigned short* eW2p   = (unsigned short*)(ws + 8912896);     // 98304 B
    unsigned short* uW1p   = (unsigned short*)(ws + 9011200);     // 196608 B
    unsigned short* uW2p   = (unsigned short*)(ws + 9207808);     // 98304 B
    unsigned short* aggG   = (unsigned short*)(ws + 9306112);     // 8388608 B

    pack_weights_k<<<1024, 256, 0, stream>>>(offW1, eW1, eW2, uW1, uW2,
                                             offW1p, eW1fp, eW2p, uW1p, uW2p);

    // initial G(0), ctr(0) from feat
    center_k<<<1024, 256, 0, stream>>>(feat, xyz, offW1p, offW2,
                                       offb1, offb2, eW1fp, Gbf, ctrb);

    for (int tt = 0; tt < 3; ++tt) {
        edge_k<<<4096, 256, 0, stream>>>(
            Gbf, xyz, knn, ctrb,
            eW1 + tt * 128 * 131, eb1 + tt * 128, eb2 + tt * 128,
            eW2p + tt * 16384, aggG);
        const float* fin = (tt == 0) ? feat : out;
        upd_k<<<2048, 256, 0, stream>>>(
            fin, out, aggG, xyz,
            uW1p + tt * 32768, uW2p + tt * 16384, ub1 + tt * 128, ub2 + tt * 128,
            eW1fp + ((tt + 1) % 3) * 16384, offW1p, offW2, offb1, offb2,
            Gbf, ctrb, (tt < 2) ? 1 : 0);
    }
}